// Round 1
// baseline (601.248 us; speedup 1.0000x reference)
//
#include <hip/hip_runtime.h>
#include <math.h>

// Problem constants
#define BATCH 32
#define H 512
#define W 512
#define OUT_HW 502          // 512 - 11 + 1
#define TS 32               // output tile (x and y)
#define IN_TS 42            // TS + 10
#define SP_STRIDE 44        // input LDS row stride (floats), mult of 4 for f4 align
#define RB_STRIDE 36        // row-blur LDS row stride (floats), mult of 4
#define NBX 16
#define NBY 16
#define NBLOCKS (NBX * NBY * BATCH)   // 8192

struct GaussW { float g[11]; };

__global__ __launch_bounds__(256, 3)
void ssim_tile_kernel(const float* __restrict__ pred,
                      const float* __restrict__ targ,
                      float* __restrict__ ws_ssim,
                      float* __restrict__ ws_mse,
                      GaussW gw)
{
    __shared__ __align__(16) float sp[IN_TS * SP_STRIDE];
    __shared__ __align__(16) float st[IN_TS * SP_STRIDE];
    __shared__ __align__(16) float rb[5][IN_TS * RB_STRIDE];
    __shared__ float red[8];

    const int tid = threadIdx.x;
    const int tx = blockIdx.x, ty = blockIdx.y, b = blockIdx.z;
    const int ox0 = tx * TS, oy0 = ty * TS;
    const int rows = min(TS, OUT_HW - oy0);   // valid output rows this tile
    const int cols = min(TS, OUT_HW - ox0);   // valid output cols this tile

    const float* __restrict__ pb = pred + (size_t)b * H * W;
    const float* __restrict__ tb = targ + (size_t)b * H * W;

    // ---- Stage 1: global -> LDS, 42 rows x 11 float4 groups (44 cols), zero pad OOB
    for (int idx = tid; idx < IN_TS * 11; idx += 256) {
        int r = idx / 11, q = idx - r * 11;
        int gy = oy0 + r, gx = ox0 + 4 * q;
        float4 vp = make_float4(0.f, 0.f, 0.f, 0.f);
        float4 vt = vp;
        if (gy < H && gx < W) {          // image width is f4-aligned: all-or-nothing
            vp = *(const float4*)(pb + (size_t)gy * W + gx);
            vt = *(const float4*)(tb + (size_t)gy * W + gx);
        }
        *(float4*)(sp + r * SP_STRIDE + 4 * q) = vp;
        *(float4*)(st + r * SP_STRIDE + 4 * q) = vt;
    }
    __syncthreads();

    // ---- MSE over this block's owned 32x32 input region (exact cover of 512x512)
    float mse_local = 0.f;
    for (int idx = tid; idx < TS * TS; idx += 256) {
        int r = idx >> 5, c = idx & 31;
        float d = sp[r * SP_STRIDE + c] - st[r * SP_STRIDE + c];
        mse_local = fmaf(d, d, mse_local);
    }

    // ---- Stage 2: horizontal blur of 5 channels into rb (float4 outputs)
    const int rrows = rows + 10;          // row-blurred rows needed
    for (int idx = tid; idx < rrows * 8; idx += 256) {
        int r = idx >> 3, gq = idx & 7;
        int c0 = 4 * gq;
        float pv[16], tv[16];
        *(float4*)(pv + 0)  = *(const float4*)(sp + r * SP_STRIDE + c0 + 0);
        *(float4*)(pv + 4)  = *(const float4*)(sp + r * SP_STRIDE + c0 + 4);
        *(float4*)(pv + 8)  = *(const float4*)(sp + r * SP_STRIDE + c0 + 8);
        *(float4*)(pv + 12) = *(const float4*)(sp + r * SP_STRIDE + c0 + 12);
        *(float4*)(tv + 0)  = *(const float4*)(st + r * SP_STRIDE + c0 + 0);
        *(float4*)(tv + 4)  = *(const float4*)(st + r * SP_STRIDE + c0 + 4);
        *(float4*)(tv + 8)  = *(const float4*)(st + r * SP_STRIDE + c0 + 8);
        *(float4*)(tv + 12) = *(const float4*)(st + r * SP_STRIDE + c0 + 12);

        float a[5][4] = {};
        #pragma unroll
        for (int k = 0; k < 11; ++k) {
            float g = gw.g[k];
            #pragma unroll
            for (int j = 0; j < 4; ++j) {
                float p = pv[j + k], t = tv[j + k];
                float gp = g * p, gt = g * t;
                a[0][j] += gp;
                a[1][j] += gt;
                a[2][j] = fmaf(gp, p, a[2][j]);
                a[3][j] = fmaf(gt, t, a[3][j]);
                a[4][j] = fmaf(gp, t, a[4][j]);
            }
        }
        #pragma unroll
        for (int ch = 0; ch < 5; ++ch) {
            float4 v = make_float4(a[ch][0], a[ch][1], a[ch][2], a[ch][3]);
            *(float4*)(&rb[ch][r * RB_STRIDE + c0]) = v;
        }
    }
    __syncthreads();

    // ---- Stage 3: vertical blur with R=4 register blocking + SSIM epilogue
    float ssim_local = 0.f;
    const int rgroups = (rows + 3) >> 2;
    if (tid < rgroups * 8) {
        int rg = tid >> 3, gq = tid & 7;
        int r0 = rg * 4, c0 = 4 * gq;
        float acc[5][4][4] = {};   // [ch][row i][col j]
        #pragma unroll
        for (int jr = 0; jr < 14; ++jr) {
            int rr = r0 + jr;
            #pragma unroll
            for (int ch = 0; ch < 5; ++ch) {
                float4 v = *(const float4*)(&rb[ch][rr * RB_STRIDE + c0]);
                #pragma unroll
                for (int i = 0; i < 4; ++i) {
                    int k = jr - i;
                    if (k >= 0 && k < 11) {
                        float g = gw.g[k];
                        acc[ch][i][0] = fmaf(g, v.x, acc[ch][i][0]);
                        acc[ch][i][1] = fmaf(g, v.y, acc[ch][i][1]);
                        acc[ch][i][2] = fmaf(g, v.z, acc[ch][i][2]);
                        acc[ch][i][3] = fmaf(g, v.w, acc[ch][i][3]);
                    }
                }
            }
        }
        const float C1 = 1e-4f, C2 = 9e-4f;
        #pragma unroll
        for (int i = 0; i < 4; ++i) {
            if (r0 + i < rows) {
                #pragma unroll
                for (int j = 0; j < 4; ++j) {
                    if (c0 + j < cols) {
                        float mu1 = acc[0][i][j], mu2 = acc[1][i][j];
                        float xx = acc[2][i][j], yy = acc[3][i][j], xy = acc[4][i][j];
                        float mu1s = mu1 * mu1, mu2s = mu2 * mu2, mu12 = mu1 * mu2;
                        float s1 = xx - mu1s;
                        float s2 = yy - mu2s;
                        float s12 = xy - mu12;
                        float num = (2.f * mu12 + C1) * (2.f * s12 + C2);
                        float den = (mu1s + mu2s + C1) * (s1 + s2 + C2) + 1e-6f;
                        ssim_local += num / den;
                    }
                }
            }
        }
    }

    // ---- Block reduction (256 threads = 4 waves)
    #pragma unroll
    for (int off = 32; off > 0; off >>= 1) {
        ssim_local += __shfl_down(ssim_local, off, 64);
        mse_local  += __shfl_down(mse_local,  off, 64);
    }
    int wave = tid >> 6;
    if ((tid & 63) == 0) { red[wave] = ssim_local; red[4 + wave] = mse_local; }
    __syncthreads();
    if (tid == 0) {
        float s = red[0] + red[1] + red[2] + red[3];
        float m = red[4] + red[5] + red[6] + red[7];
        int bid = (b * NBY + ty) * NBX + tx;
        ws_ssim[bid] = s;
        ws_mse[bid]  = m;
    }
}

__global__ __launch_bounds__(256)
void finalize_kernel(const float* __restrict__ ws_ssim,
                     const float* __restrict__ ws_mse,
                     float* __restrict__ out)
{
    __shared__ double rs[256], rm[256];
    int tid = threadIdx.x;
    double s = 0.0, m = 0.0;
    for (int i = tid; i < NBLOCKS; i += 256) {
        s += (double)ws_ssim[i];
        m += (double)ws_mse[i];
    }
    rs[tid] = s; rm[tid] = m;
    __syncthreads();
    for (int off = 128; off > 0; off >>= 1) {
        if (tid < off) { rs[tid] += rs[tid + off]; rm[tid] += rm[tid + off]; }
        __syncthreads();
    }
    if (tid == 0) {
        double mse_mean  = rm[0] / (double)((size_t)BATCH * H * W);
        double ssim_mean = rs[0] / (double)((size_t)BATCH * OUT_HW * OUT_HW);
        out[0] = (float)(0.6 * mse_mean + 0.4 * (1.0 - ssim_mean));
    }
}

extern "C" void kernel_launch(void* const* d_in, const int* in_sizes, int n_in,
                              void* d_out, int out_size, void* d_ws, size_t ws_size,
                              hipStream_t stream)
{
    const float* pred = (const float*)d_in[0];
    const float* targ = (const float*)d_in[1];
    float* out = (float*)d_out;
    float* ws_ssim = (float*)d_ws;
    float* ws_mse  = ws_ssim + NBLOCKS;

    // Gaussian taps: computed host-side in double, normalized, passed by value.
    GaussW gw;
    double g[11], sum = 0.0;
    for (int i = 0; i < 11; ++i) { double x = i - 5.0; g[i] = exp(-x * x / 4.5); sum += g[i]; }
    for (int i = 0; i < 11; ++i) gw.g[i] = (float)(g[i] / sum);

    ssim_tile_kernel<<<dim3(NBX, NBY, BATCH), 256, 0, stream>>>(pred, targ, ws_ssim, ws_mse, gw);
    finalize_kernel<<<1, 256, 0, stream>>>(ws_ssim, ws_mse, out);
}

// Round 2
// 258.041 us; speedup vs baseline: 2.3301x; 2.3301x over previous
//
#include <hip/hip_runtime.h>
#include <math.h>

// Problem constants
#define BATCH 32
#define H 512
#define W 512
#define OUT_HW 502          // 512 - 11 + 1
#define TS 32               // output tile (x and y)
#define IN_TS 42            // TS + 10
#define SP_STRIDE 44        // input LDS row stride (floats), mult of 4 for f4 align
#define RB_STRIDE 36        // row-blur LDS row stride (floats), mult of 4
#define NBX 16
#define NBY 16
#define NBLOCKS (NBX * NBY * BATCH)   // 8192

struct GaussW { float g[11]; };

// NOTE: __launch_bounds__(256,3) caused the R1 disaster: it caps VGPR at 170,
// the 80-float stage-3 accumulator spilled to scratch (280 MB HBM writes,
// VALUBusy 7.6%). Occupancy is LDS-bound at 3 blocks/CU anyway, so allow up
// to 256 VGPR (min 2 waves/EU).
__global__ __launch_bounds__(256, 2)
void ssim_tile_kernel(const float* __restrict__ pred,
                      const float* __restrict__ targ,
                      float* __restrict__ ws_ssim,
                      float* __restrict__ ws_mse,
                      GaussW gw)
{
    __shared__ __align__(16) float sp[IN_TS * SP_STRIDE];
    __shared__ __align__(16) float st[IN_TS * SP_STRIDE];
    __shared__ __align__(16) float rb[5][IN_TS * RB_STRIDE];
    __shared__ float red[8];

    const int tid = threadIdx.x;
    const int tx = blockIdx.x, ty = blockIdx.y, b = blockIdx.z;
    const int ox0 = tx * TS, oy0 = ty * TS;
    const int rows = min(TS, OUT_HW - oy0);   // valid output rows this tile
    const int cols = min(TS, OUT_HW - ox0);   // valid output cols this tile

    const float* __restrict__ pb = pred + (size_t)b * H * W;
    const float* __restrict__ tb = targ + (size_t)b * H * W;

    // ---- Stage 1: global -> LDS, 42 rows x 11 float4 groups (44 cols), zero pad OOB
    for (int idx = tid; idx < IN_TS * 11; idx += 256) {
        int r = idx / 11, q = idx - r * 11;
        int gy = oy0 + r, gx = ox0 + 4 * q;
        float4 vp = make_float4(0.f, 0.f, 0.f, 0.f);
        float4 vt = vp;
        if (gy < H && gx < W) {          // image width is f4-aligned: all-or-nothing
            vp = *(const float4*)(pb + (size_t)gy * W + gx);
            vt = *(const float4*)(tb + (size_t)gy * W + gx);
        }
        *(float4*)(sp + r * SP_STRIDE + 4 * q) = vp;
        *(float4*)(st + r * SP_STRIDE + 4 * q) = vt;
    }
    __syncthreads();

    // ---- MSE over this block's owned 32x32 input region (exact cover of 512x512)
    float mse_local = 0.f;
    for (int idx = tid; idx < TS * TS; idx += 256) {
        int r = idx >> 5, c = idx & 31;
        float d = sp[r * SP_STRIDE + c] - st[r * SP_STRIDE + c];
        mse_local = fmaf(d, d, mse_local);
    }

    // ---- Stage 2: horizontal blur of 5 channels into rb (float4 outputs)
    const int rrows = rows + 10;          // row-blurred rows needed
    for (int idx = tid; idx < rrows * 8; idx += 256) {
        int r = idx >> 3, gq = idx & 7;
        int c0 = 4 * gq;
        float pv[16], tv[16];
        *(float4*)(pv + 0)  = *(const float4*)(sp + r * SP_STRIDE + c0 + 0);
        *(float4*)(pv + 4)  = *(const float4*)(sp + r * SP_STRIDE + c0 + 4);
        *(float4*)(pv + 8)  = *(const float4*)(sp + r * SP_STRIDE + c0 + 8);
        *(float4*)(pv + 12) = *(const float4*)(sp + r * SP_STRIDE + c0 + 12);
        *(float4*)(tv + 0)  = *(const float4*)(st + r * SP_STRIDE + c0 + 0);
        *(float4*)(tv + 4)  = *(const float4*)(st + r * SP_STRIDE + c0 + 4);
        *(float4*)(tv + 8)  = *(const float4*)(st + r * SP_STRIDE + c0 + 8);
        *(float4*)(tv + 12) = *(const float4*)(st + r * SP_STRIDE + c0 + 12);

        float a[5][4] = {};
        #pragma unroll
        for (int k = 0; k < 11; ++k) {
            float g = gw.g[k];
            #pragma unroll
            for (int j = 0; j < 4; ++j) {
                float p = pv[j + k], t = tv[j + k];
                float gp = g * p, gt = g * t;
                a[0][j] += gp;
                a[1][j] += gt;
                a[2][j] = fmaf(gp, p, a[2][j]);
                a[3][j] = fmaf(gt, t, a[3][j]);
                a[4][j] = fmaf(gp, t, a[4][j]);
            }
        }
        #pragma unroll
        for (int ch = 0; ch < 5; ++ch) {
            float4 v = make_float4(a[ch][0], a[ch][1], a[ch][2], a[ch][3]);
            *(float4*)(&rb[ch][r * RB_STRIDE + c0]) = v;
        }
    }
    __syncthreads();

    // ---- Stage 3: vertical blur with R=4 register blocking + SSIM epilogue
    float ssim_local = 0.f;
    const int rgroups = (rows + 3) >> 2;
    if (tid < rgroups * 8) {
        int rg = tid >> 3, gq = tid & 7;
        int r0 = rg * 4, c0 = 4 * gq;
        float acc[5][4][4] = {};   // [ch][row i][col j]
        #pragma unroll
        for (int jr = 0; jr < 14; ++jr) {
            int rr = r0 + jr;
            #pragma unroll
            for (int ch = 0; ch < 5; ++ch) {
                float4 v = *(const float4*)(&rb[ch][rr * RB_STRIDE + c0]);
                #pragma unroll
                for (int i = 0; i < 4; ++i) {
                    int k = jr - i;
                    if (k >= 0 && k < 11) {
                        float g = gw.g[k];
                        acc[ch][i][0] = fmaf(g, v.x, acc[ch][i][0]);
                        acc[ch][i][1] = fmaf(g, v.y, acc[ch][i][1]);
                        acc[ch][i][2] = fmaf(g, v.z, acc[ch][i][2]);
                        acc[ch][i][3] = fmaf(g, v.w, acc[ch][i][3]);
                    }
                }
            }
        }
        const float C1 = 1e-4f, C2 = 9e-4f;
        #pragma unroll
        for (int i = 0; i < 4; ++i) {
            if (r0 + i < rows) {
                #pragma unroll
                for (int j = 0; j < 4; ++j) {
                    if (c0 + j < cols) {
                        float mu1 = acc[0][i][j], mu2 = acc[1][i][j];
                        float xx = acc[2][i][j], yy = acc[3][i][j], xy = acc[4][i][j];
                        float mu1s = mu1 * mu1, mu2s = mu2 * mu2, mu12 = mu1 * mu2;
                        float s1 = xx - mu1s;
                        float s2 = yy - mu2s;
                        float s12 = xy - mu12;
                        float num = (2.f * mu12 + C1) * (2.f * s12 + C2);
                        float den = (mu1s + mu2s + C1) * (s1 + s2 + C2) + 1e-6f;
                        ssim_local += num / den;
                    }
                }
            }
        }
    }

    // ---- Block reduction (256 threads = 4 waves)
    #pragma unroll
    for (int off = 32; off > 0; off >>= 1) {
        ssim_local += __shfl_down(ssim_local, off, 64);
        mse_local  += __shfl_down(mse_local,  off, 64);
    }
    int wave = tid >> 6;
    if ((tid & 63) == 0) { red[wave] = ssim_local; red[4 + wave] = mse_local; }
    __syncthreads();
    if (tid == 0) {
        float s = red[0] + red[1] + red[2] + red[3];
        float m = red[4] + red[5] + red[6] + red[7];
        int bid = (b * NBY + ty) * NBX + tx;
        ws_ssim[bid] = s;
        ws_mse[bid]  = m;
    }
}

__global__ __launch_bounds__(256)
void finalize_kernel(const float* __restrict__ ws_ssim,
                     const float* __restrict__ ws_mse,
                     float* __restrict__ out)
{
    __shared__ double rs[256], rm[256];
    int tid = threadIdx.x;
    double s = 0.0, m = 0.0;
    for (int i = tid; i < NBLOCKS; i += 256) {
        s += (double)ws_ssim[i];
        m += (double)ws_mse[i];
    }
    rs[tid] = s; rm[tid] = m;
    __syncthreads();
    for (int off = 128; off > 0; off >>= 1) {
        if (tid < off) { rs[tid] += rs[tid + off]; rm[tid] += rm[tid + off]; }
        __syncthreads();
    }
    if (tid == 0) {
        double mse_mean  = rm[0] / (double)((size_t)BATCH * H * W);
        double ssim_mean = rs[0] / (double)((size_t)BATCH * OUT_HW * OUT_HW);
        out[0] = (float)(0.6 * mse_mean + 0.4 * (1.0 - ssim_mean));
    }
}

extern "C" void kernel_launch(void* const* d_in, const int* in_sizes, int n_in,
                              void* d_out, int out_size, void* d_ws, size_t ws_size,
                              hipStream_t stream)
{
    const float* pred = (const float*)d_in[0];
    const float* targ = (const float*)d_in[1];
    float* out = (float*)d_out;
    float* ws_ssim = (float*)d_ws;
    float* ws_mse  = ws_ssim + NBLOCKS;

    // Gaussian taps: computed host-side in double, normalized, passed by value.
    GaussW gw;
    double g[11], sum = 0.0;
    for (int i = 0; i < 11; ++i) { double x = i - 5.0; g[i] = exp(-x * x / 4.5); sum += g[i]; }
    for (int i = 0; i < 11; ++i) gw.g[i] = (float)(g[i] / sum);

    ssim_tile_kernel<<<dim3(NBX, NBY, BATCH), 256, 0, stream>>>(pred, targ, ws_ssim, ws_mse, gw);
    finalize_kernel<<<1, 256, 0, stream>>>(ws_ssim, ws_mse, out);
}